// Round 7
// baseline (726.463 us; speedup 1.0000x reference)
//
#include <hip/hip_runtime.h>

// ---------------------------------------------------------------------------
// Problem constants: B=2048, NS=8, S=8, H=512, WH=1, WK=32, RH=4, RK=32, T=16.
// ---------------------------------------------------------------------------
#define Bb   2048
#define Mrows 16384   // B*8
#define Hd   512

typedef float  f32x4  __attribute__((ext_vector_type(4)));
typedef __bf16 bf16x8 __attribute__((ext_vector_type(8)));
typedef unsigned short us8 __attribute__((ext_vector_type(8)));

__device__ __forceinline__ unsigned short f2bf(float f) {
    unsigned int u = __builtin_bit_cast(unsigned int, f);
    u = u + 0x7FFFu + ((u >> 16) & 1u);   // round-to-nearest-even
    return (unsigned short)(u >> 16);
}
__device__ __forceinline__ float bf2f(unsigned short h) {
    unsigned int u = ((unsigned int)h) << 16;
    return __builtin_bit_cast(float, u);
}

// async global->LDS DMA, 16B per lane; lds dest = wave-uniform base + lane*16
__device__ __forceinline__ void gload_lds16(const unsigned short* g, void* lds) {
    __builtin_amdgcn_global_load_lds(
        (const __attribute__((address_space(1))) unsigned int*)g,
        (__attribute__((address_space(3))) unsigned int*)lds,
        16, 0, 0);
}

// ---------------------------------------------------------------------------
// Workspace layout (bytes); aliases verified by lifetime (rounds 1-6 passed).
// ---------------------------------------------------------------------------
#define MB (1024ull*1024ull)
#define OFF_WQ   0ull
#define OFF_WK   32768ull
#define OFF_WV   65536ull
#define OFF_WO   589824ull
#define OFF_UT   1114112ull
#define OFF_UG   1638400ull
#define OFF_RQ   2686976ull
#define OFF_RK   2818048ull
#define OFF_RV   2949120ull
#define OFF_RO   5046272ull
#define OFF_HS    (8*MB)
#define OFF_MEM   (24*MB)
#define OFF_UTR   (40*MB)
#define OFF_Q1    (60*MB)
#define OFF_K1    (62*MB)
#define OFF_V1    (66*MB)
#define OFF_CTX1  (100*MB)
#define OFF_KK    (116*MB)
#define OFF_TMW   (132*MB)
#define OFF_GATES (148*MB)
#define OFF_MNB   (180*MB)
#define OFF_Q2    (196*MB)
#define OFF_K2    (204*MB)
#define OFF_RVO   (40*MB)    // alias: UTR/Q1/K1/V1/CTX1[0:4MB] dead by then
#define OFF_CTX2  (104*MB)   // alias: CTX1[4:]/KK/TMW/GATES[0:20MB] dead by then

// ---------------------------------------------------------------------------
// Cast f32 -> bf16, 12 segments in one kernel
// ---------------------------------------------------------------------------
struct CastSeg { const float* src; unsigned short* dst; int n4; };
struct CastParams { CastSeg seg[12]; };

__global__ __launch_bounds__(256) void cast_all(CastParams p) {
    CastSeg s = p.seg[blockIdx.y];
    int stride = gridDim.x * blockDim.x;
    for (int i = blockIdx.x * blockDim.x + threadIdx.x; i < s.n4; i += stride) {
        float4 v = reinterpret_cast<const float4*>(s.src)[i];
        ushort4 o;
        o.x = f2bf(v.x); o.y = f2bf(v.y); o.z = f2bf(v.z); o.w = f2bf(v.w);
        reinterpret_cast<ushort4*>(s.dst)[i] = o;
    }
}

// ---------------------------------------------------------------------------
// Epilogue.  MODE: 0 f32  1 bf16  2 relu->bf16  3 sigmoid->bf16
// 4 tanh->bf16  5 f32+row-remap  6 bf16+row-remap  7 f32+residual
// ---------------------------------------------------------------------------
template<int MODE>
__device__ __forceinline__ void store_c(void* out, const float* extra, int row,
                                        int col, int ldo, int remap_off, float v) {
    if (MODE == 0) {
        ((float*)out)[(size_t)row * ldo + col] = v;
    } else if (MODE == 1) {
        ((unsigned short*)out)[(size_t)row * ldo + col] = f2bf(v);
    } else if (MODE == 2) {
        ((unsigned short*)out)[(size_t)row * ldo + col] = f2bf(fmaxf(v, 0.f));
    } else if (MODE == 3) {
        ((unsigned short*)out)[(size_t)row * ldo + col] = f2bf(1.f / (1.f + expf(-v)));
    } else if (MODE == 4) {
        ((unsigned short*)out)[(size_t)row * ldo + col] = f2bf(tanhf(v));
    } else if (MODE == 5) {
        int rr = ((row >> 3) << 4) + (row & 7) + remap_off;
        ((float*)out)[(size_t)rr * ldo + col] = v;
    } else if (MODE == 6) {
        int rr = ((row >> 3) << 4) + (row & 7) + remap_off;
        ((unsigned short*)out)[(size_t)rr * ldo + col] = f2bf(v);
    } else if (MODE == 7) {
        ((float*)out)[(size_t)row * ldo + col] = v + extra[(size_t)row * ldo + col];
    }
}

// ---------------------------------------------------------------------------
// Multi-segment GEMM, R3-proven K-loop (measured best: 510 TF on rv class):
//   128x128 block tile, BK=64, 4 waves (2x2), wave tile 64x64.
//   SINGLE LDS buffer (As+Bs = 32 KB) -> 5 blocks/CU at (256,5); occupancy
//   (not explicit pipelining) provides the overlap — R4/R6 A/B showed dbuf
//   and BK=32 variants both regress (bank conflicts / exposed latency).
//   K-step: syncthreads (drain DMAs); ds_read+MFMA; syncthreads; stage kt+1.
//   XOR 16B-chunk swizzle on the GLOBAL source address (LDS linear, m173);
//   ds_read slot = kc ^ (row&7) over 8 slots -> verified 0 bank conflicts.
// ---------------------------------------------------------------------------
struct GemmSeg {
    const unsigned short* A;
    const unsigned short* W;
    const float* bias;
    void* out;
    const float* extra;
    int mode, ldo, remap_off, tile0;
};
struct GemmParams { GemmSeg seg[4]; int nseg; int tiles_tot; };

template<int K>
__global__ __launch_bounds__(256, 5) void gemm_multi(GemmParams p)
{
    constexpr int NT = K / 64;
    __shared__ __align__(16) unsigned short As[128 * 64];
    __shared__ __align__(16) unsigned short Bs[128 * 64];

    // bijective XCD-chunk swizzle (grid always a multiple of 8)
    const int nwg = (int)gridDim.x;
    const int swz = ((int)blockIdx.x & 7) * (nwg >> 3) + ((int)blockIdx.x >> 3);
    const int bm = swz / p.tiles_tot;
    const int tl = swz - bm * p.tiles_tot;

    int si = 0;
    #pragma unroll
    for (int i = 1; i < 4; i++)
        if (i < p.nseg && tl >= p.seg[i].tile0) si = i;
    const unsigned short* Aseg = p.seg[si].A;
    const unsigned short* Wseg = p.seg[si].W;
    const int bn = tl - p.seg[si].tile0;

    const int t = threadIdx.x;
    const int wave = t >> 6, lane = t & 63;
    const int wr = (wave >> 1) * 64;
    const int wc = (wave & 1) * 64;
    const int lrow = lane & 15;
    const int lkh  = lane >> 4;            // 0..3 (k-chunk of fragment)

    // staging: chunk c = wave*256 + j*64 + lane; row=c>>3, slot=c&7;
    // LDS linear (chunk c at byte c*16); source k-chunk = slot ^ (row&7)
    const unsigned short* ga[4];
    const unsigned short* gb[4];
    #pragma unroll
    for (int j = 0; j < 4; j++) {
        int c   = wave * 256 + j * 64 + lane;
        int row = c >> 3;
        int kl  = (c & 7) ^ (row & 7);
        ga[j] = Aseg + (size_t)(bm * 128 + row) * K + kl * 8;
        gb[j] = Wseg + (size_t)(bn * 128 + row) * K + kl * 8;
    }

    // fragment ds_read offsets (elements, swizzled)
    int aof[4][2], bof[4][2];
    #pragma unroll
    for (int m = 0; m < 4; m++) {
        int ra = wr + m * 16 + lrow;
        int rb = wc + m * 16 + lrow;
        #pragma unroll
        for (int kk = 0; kk < 2; kk++) {
            int kc = kk * 4 + lkh;
            aof[m][kk] = ra * 64 + ((kc ^ (ra & 7)) << 3);
            bof[m][kk] = rb * 64 + ((kc ^ (rb & 7)) << 3);
        }
    }

    f32x4 acc[4][4] = {};

    // prologue: stage tile 0
    #pragma unroll
    for (int j = 0; j < 4; j++) {
        gload_lds16(ga[j], (char*)As + (wave * 4 + j) * 1024);
        gload_lds16(gb[j], (char*)Bs + (wave * 4 + j) * 1024);
    }

    for (int kt = 0; kt < NT; ++kt) {
        __syncthreads();   // drains vmcnt -> tile kt resident in LDS
        #pragma unroll
        for (int kk = 0; kk < 2; kk++) {
            bf16x8 af[4], bfr[4];
            #pragma unroll
            for (int m = 0; m < 4; m++)
                af[m] = __builtin_bit_cast(bf16x8,
                            *reinterpret_cast<const us8*>(&As[aof[m][kk]]));
            #pragma unroll
            for (int n = 0; n < 4; n++)
                bfr[n] = __builtin_bit_cast(bf16x8,
                            *reinterpret_cast<const us8*>(&Bs[bof[n][kk]]));
            #pragma unroll
            for (int m = 0; m < 4; m++)
                #pragma unroll
                for (int n = 0; n < 4; n++)
                    acc[m][n] = __builtin_amdgcn_mfma_f32_16x16x32_bf16(
                                    af[m], bfr[n], acc[m][n], 0, 0, 0);
        }
        __syncthreads();   // all waves done reading tile kt
        if (kt + 1 < NT) {
            #pragma unroll
            for (int j = 0; j < 4; j++) {
                gload_lds16(ga[j] + (kt + 1) * 64, (char*)As + (wave * 4 + j) * 1024);
                gload_lds16(gb[j] + (kt + 1) * 64, (char*)Bs + (wave * 4 + j) * 1024);
            }
        }
    }

    // epilogue (uniform branch on segment mode)
    void* outp = p.seg[si].out;
    const float* bias = p.seg[si].bias;
    const float* extra = p.seg[si].extra;
    const int ldo = p.seg[si].ldo, rmo = p.seg[si].remap_off, mode = p.seg[si].mode;

    #define EPI(MODE_)                                                          \
        _Pragma("unroll")                                                       \
        for (int n = 0; n < 4; n++) {                                           \
            int col = bn * 128 + wc + n * 16 + lrow;                            \
            float bv = bias[col];                                               \
            _Pragma("unroll")                                                   \
            for (int m = 0; m < 4; m++) {                                       \
                _Pragma("unroll")                                               \
                for (int r = 0; r < 4; r++) {                                   \
                    int row = bm * 128 + wr + m * 16 + lkh * 4 + r;             \
                    store_c<MODE_>(outp, extra, row, col, ldo, rmo,             \
                                   acc[m][n][r] + bv);                          \
                }                                                               \
            }                                                                   \
        }
    switch (mode) {
        case 0: EPI(0) break;
        case 1: EPI(1) break;
        case 2: EPI(2) break;
        case 3: EPI(3) break;
        case 4: EPI(4) break;
        case 5: EPI(5) break;
        case 6: EPI(6) break;
        default: EPI(7) break;
    }
    #undef EPI
}

// ---------------------------------------------------------------------------
// Fused small GEMMs (N=32, K=512): 3 segments in one dispatch, 256 blocks
// each (bm over M/64).  Direct-global fragments.  Modes: 0 (f32) / 5 (remap).
// ---------------------------------------------------------------------------
struct SmallSeg {
    const unsigned short* A;
    const unsigned short* W;
    const float* bias;
    float* out;
    int mode, remap_off;
};
struct SmallParams { SmallSeg seg[3]; };

__global__ __launch_bounds__(256) void gemm_small3(SmallParams p)
{
    constexpr int K = 512;
    const int si = blockIdx.x >> 8;
    const int bm = blockIdx.x & 255;
    const SmallSeg s = p.seg[si];

    const int wave = threadIdx.x >> 6;
    const int lane = threadIdx.x & 63;
    const int row0 = bm * 64 + wave * 16;
    const int lrow = lane & 15;
    const int lk   = (lane >> 4) << 3;

    f32x4 acc[2] = {};
    const unsigned short* ap  = s.A + (size_t)(row0 + lrow) * K + lk;
    const unsigned short* wp0 = s.W + (size_t)lrow * K + lk;

    #pragma unroll 4
    for (int ks = 0; ks < K; ks += 32) {
        bf16x8 af = __builtin_bit_cast(bf16x8,
                        *reinterpret_cast<const us8*>(ap + ks));
        #pragma unroll
        for (int tt = 0; tt < 2; tt++) {
            bf16x8 bfm = __builtin_bit_cast(bf16x8,
                        *reinterpret_cast<const us8*>(wp0 + (size_t)tt * 16 * K + ks));
            acc[tt] = __builtin_amdgcn_mfma_f32_16x16x32_bf16(af, bfm, acc[tt], 0, 0, 0);
        }
    }

    #pragma unroll
    for (int tt = 0; tt < 2; tt++) {
        int col = tt * 16 + lrow;
        float bv = s.bias[col];
        #pragma unroll
        for (int r = 0; r < 4; r++) {
            int row = row0 + (lane >> 4) * 4 + r;
            float v = acc[tt][r] + bv;
            if (s.mode == 0) {
                s.out[(size_t)row * 32 + col] = v;
            } else {
                int rr = ((row >> 3) << 4) + (row & 7) + s.remap_off;
                s.out[(size_t)rr * 32 + col] = v;
            }
        }
    }
}

// ---------------------------------------------------------------------------
// fused: mean over NS=8 relu rows, then kk = mean + tanh(mem) -> bf16
// block = one batch; thread covers cols {tid, tid+256} for all 8 rows
// ---------------------------------------------------------------------------
__global__ __launch_bounds__(256) void meankk_kernel(
    const unsigned short* __restrict__ UTR, const float* __restrict__ mem,
    unsigned short* __restrict__ KK)
{
    int b = blockIdx.x;
    #pragma unroll
    for (int half = 0; half < 2; half++) {
        int j = threadIdx.x + half * 256;
        float sum = 0.f;
        #pragma unroll
        for (int r = 0; r < 8; r++)
            sum += bf2f(UTR[((size_t)(b * 8 + r) << 9) + j]);
        float mn = sum * 0.125f;
        #pragma unroll
        for (int r = 0; r < 8; r++) {
            size_t idx = ((size_t)(b * 8 + r) << 9) + j;
            KK[idx] = f2bf(mn + tanhf(mem[idx]));
        }
    }
}

// mem_new = sig(ig)*tanh(mem_write) + sig(fg)*mem, x4 vectorized
__global__ __launch_bounds__(256) void memnew_kernel(
    const unsigned short* __restrict__ GATES, const unsigned short* __restrict__ TMW,
    const float* __restrict__ mem, float* __restrict__ out_mem,
    unsigned short* __restrict__ MNB)
{
    int idx = blockIdx.x * 256 + threadIdx.x;   // float4 units: 16384*128
    int m = idx >> 7, j4 = idx & 127;
    ushort4 ig4 = reinterpret_cast<const ushort4*>(GATES + (size_t)m * 1024)[j4];
    ushort4 fg4 = reinterpret_cast<const ushort4*>(GATES + (size_t)m * 1024 + 512)[j4];
    ushort4 tm4 = reinterpret_cast<const ushort4*>(TMW + (size_t)m * 512)[j4];
    float4  mm  = reinterpret_cast<const float4*>(mem + (size_t)m * 512)[j4];
    float4 v;
    v.x = bf2f(ig4.x) * bf2f(tm4.x) + bf2f(fg4.x) * mm.x;
    v.y = bf2f(ig4.y) * bf2f(tm4.y) + bf2f(fg4.y) * mm.y;
    v.z = bf2f(ig4.z) * bf2f(tm4.z) + bf2f(fg4.z) * mm.z;
    v.w = bf2f(ig4.w) * bf2f(tm4.w) + bf2f(fg4.w) * mm.w;
    reinterpret_cast<float4*>(out_mem + (size_t)m * 512)[j4] = v;
    ushort4 o; o.x = f2bf(v.x); o.y = f2bf(v.y); o.z = f2bf(v.z); o.w = f2bf(v.w);
    reinterpret_cast<ushort4*>(MNB + (size_t)m * 512)[j4] = o;
}

// ---------------------------------------------------------------------------
// Attention 1: per batch, q(8,32) k(16,32) v(16,512) -> ctx(8,512) bf16
// ---------------------------------------------------------------------------
__global__ __launch_bounds__(256) void attn1_kernel(
    const float* __restrict__ Q1, const float* __restrict__ K1,
    const unsigned short* __restrict__ V1, unsigned short* __restrict__ CTX1)
{
    int b = blockIdx.x, t = threadIdx.x;
    __shared__ float q[8][32], k[16][32], pr[8][16];
    q[t >> 5][t & 31] = Q1[(size_t)b * 256 + t];
    k[t >> 5][t & 31]       = K1[(size_t)b * 512 + t];
    k[8 + (t >> 5)][t & 31] = K1[(size_t)b * 512 + 256 + t];
    __syncthreads();
    if (t < 128) {
        int s = t >> 4, tt = t & 15;
        float acc = 0.f;
        #pragma unroll
        for (int i = 0; i < 32; i++) acc += q[s][i] * k[tt][i];
        pr[s][tt] = acc * 0.17677669529663687f;   // 1/sqrt(32)
    }
    __syncthreads();
    if (t < 8) {
        float m = -1e30f;
        for (int i = 0; i < 16; i++) m = fmaxf(m, pr[t][i]);
        float e[16], sum = 0.f;
        for (int i = 0; i < 16; i++) { e[i] = expf(pr[t][i] - m); sum += e[i]; }
        float inv = 1.f / sum;
        for (int i = 0; i < 16; i++) pr[t][i] = e[i] * inv;
    }
    __syncthreads();
    int s = t >> 5, d0 = (t & 31) * 16;
    float a[16];
    #pragma unroll
    for (int i = 0; i < 16; i++) a[i] = 0.f;
    for (int tt = 0; tt < 16; tt++) {
        float p = pr[s][tt];
        const unsigned short* vp = V1 + ((size_t)(b * 16 + tt)) * 512 + d0;
        us8 v0 = *reinterpret_cast<const us8*>(vp);
        us8 v1 = *reinterpret_cast<const us8*>(vp + 8);
        #pragma unroll
        for (int i = 0; i < 8; i++) a[i]     += p * bf2f(v0[i]);
        #pragma unroll
        for (int i = 0; i < 8; i++) a[8 + i] += p * bf2f(v1[i]);
    }
    us8 o0, o1;
    #pragma unroll
    for (int i = 0; i < 8; i++) { o0[i] = f2bf(a[i]); o1[i] = f2bf(a[8 + i]); }
    unsigned short* cp = CTX1 + ((size_t)(b * 8 + s)) * 512 + d0;
    *reinterpret_cast<us8*>(cp) = o0;
    *reinterpret_cast<us8*>(cp + 8) = o1;
}

// ---------------------------------------------------------------------------
// Attention 2: per batch, 4 heads: q(8,32) k(8,32) v(8,512) -> ctx(8,2048)
// ---------------------------------------------------------------------------
__global__ __launch_bounds__(256) void attn2_kernel(
    const float* __restrict__ Q2, const float* __restrict__ K2,
    const unsigned short* __restrict__ V2, unsigned short* __restrict__ CTX2)
{
    int b = blockIdx.x, t = threadIdx.x;
    __shared__ float q[8][128], k[8][128], pr[4][8][8];
    for (int i = t; i < 1024; i += 256) {
        q[i >> 7][i & 127] = Q2[(size_t)b * 1024 + i];
        k[i >> 7][i & 127] = K2[(size_t)b * 1024 + i];
    }
    __syncthreads();
    {
        int h = t >> 6, n = (t >> 3) & 7, s = t & 7;
        float acc = 0.f;
        #pragma unroll
        for (int i = 0; i < 32; i++) acc += q[n][h * 32 + i] * k[s][h * 32 + i];
        pr[h][n][s] = acc * 0.17677669529663687f;
    }
    __syncthreads();
    if (t < 32) {
        int h = t >> 3, n = t & 7;
        float m = -1e30f;
        for (int i = 0; i < 8; i++) m = fmaxf(m, pr[h][n][i]);
        float e[8], sum = 0.f;
        for (int i = 0; i < 8; i++) { e[i] = expf(pr[h][n][i] - m); sum += e[i]; }
        float inv = 1.f / sum;
        for (int i = 0; i < 8; i++) pr[h][n][i] = e[i] * inv;
    }
    __syncthreads();
    int n = t >> 5, d0 = (t & 31) * 16;
    for (int h = 0; h < 4; h++) {
        float a[16];
        #pragma unroll
        for (int i = 0; i < 16; i++) a[i] = 0.f;
        for (int s = 0; s < 8; s++) {
            float p = pr[h][n][s];
            const unsigned short* vp = V2 + ((size_t)(b * 8 + s)) * 2048 + h * 512 + d0;
            us8 v0 = *reinterpret_cast<const us8*>(vp);
            us8 v1 = *reinterpret_cast<const us8*>(vp + 8);
            #pragma unroll
            for (int i = 0; i < 8; i++) a[i]     += p * bf2f(v0[i]);
            #pragma unroll
            for (int i = 0; i < 8; i++) a[8 + i] += p * bf2f(v1[i]);
        }
        us8 o0, o1;
        #pragma unroll
        for (int i = 0; i < 8; i++) { o0[i] = f2bf(a[i]); o1[i] = f2bf(a[8 + i]); }
        unsigned short* cp = CTX2 + ((size_t)(b * 8 + n)) * 2048 + h * 512 + d0;
        *reinterpret_cast<us8*>(cp) = o0;
        *reinterpret_cast<us8*>(cp + 8) = o1;
    }
}

// ---------------------------------------------------------------------------
extern "C" void kernel_launch(void* const* d_in, const int* in_sizes, int n_in,
                              void* d_out, int out_size, void* d_ws, size_t ws_size,
                              hipStream_t stream)
{
    const float* h_s  = (const float*)d_in[0];
    const float* mem  = (const float*)d_in[1];
    const float* wq_w = (const float*)d_in[2];  const float* wq_b = (const float*)d_in[3];
    const float* wk_w = (const float*)d_in[4];  const float* wk_b = (const float*)d_in[5];
    const float* wv_w = (const float*)d_in[6];  const float* wv_b = (const float*)d_in[7];
    const float* wo_w = (const float*)d_in[8];  const float* wo_b = (const float*)d_in[9];
    const float* ut_w = (const float*)d_in[10]; const float* ut_b = (const float*)d_in[11];
    const float* ug_w = (const float*)d_in[12]; const float* ug_b = (const float*)d_in[13];
    const float* rq_w = (const float*)d_in[14]; const float* rq_b = (const float*)d_in[15];
    const float* rk_w = (const float*)d_in[16]; const float* rk_b = (const float*)d_in[17];
    const float* rv_w = (const float*)d_in[18]; const float* rv_b = (const float*)d_in[19];
    const float* ro_w = (const float*)d_in[20]; const float* ro_b = (const float*)d_in[21];

    char* ws = (char*)d_ws;
    unsigned short* WQb = (unsigned short*)(ws + OFF_WQ);
    unsigned short* WKb = (unsigned short*)(ws + OFF_WK);
    unsigned short* WVb = (unsigned short*)(ws + OFF_WV);
    unsigned short* WOb = (unsigned short*)(ws + OFF_WO);
    unsigned short* UTb = (unsigned short*)(ws + OFF_UT);
    unsigned short* UGb = (unsigned short*)(ws + OFF_UG);
    unsigned short* RQb = (unsigned short*)(ws + OFF_RQ);
    unsigned short* RKb = (unsigned short*)(ws + OFF_RK);
    unsigned short* RVb = (unsigned short*)(ws + OFF_RV);
    unsigned short* ROb = (unsigned short*)(ws + OFF_RO);
    unsigned short* HSb  = (unsigned short*)(ws + OFF_HS);
    unsigned short* MEMb = (unsigned short*)(ws + OFF_MEM);
    unsigned short* UTR  = (unsigned short*)(ws + OFF_UTR);
    float*          Q1   = (float*)(ws + OFF_Q1);
    float*          K1   = (float*)(ws + OFF_K1);
    unsigned short* V1   = (unsigned short*)(ws + OFF_V1);
    unsigned short* CTX1 = (unsigned short*)(ws + OFF_CTX1);
    unsigned short* KKb  = (unsigned short*)(ws + OFF_KK);
    unsigned short* TMW  = (unsigned short*)(ws + OFF_TMW);
    unsigned short* GATES= (unsigned short*)(ws + OFF_GATES);
    unsigned short* MNB  = (unsigned short*)(ws + OFF_MNB);
    float*          Q2   = (float*)(ws + OFF_Q2);
    float*          K2   = (float*)(ws + OFF_K2);
    unsigned short* RVO  = (unsigned short*)(ws + OFF_RVO);
    unsigned short* CTX2 = (unsigned short*)(ws + OFF_CTX2);

    float* out   = (float*)d_out;            // h_out (16384,512)
    float* out_m = out + (size_t)Mrows * Hd; // mem_new (16384,512)

    // 1) cast inputs + weights to bf16
    CastParams cp;
    cp.seg[0]  = { h_s,  HSb,  (Mrows * Hd) / 4 };
    cp.seg[1]  = { mem,  MEMb, (Mrows * Hd) / 4 };
    cp.seg[2]  = { wq_w, WQb,  (32 * 512) / 4 };
    cp.seg[3]  = { wk_w, WKb,  (32 * 512) / 4 };
    cp.seg[4]  = { wv_w, WVb,  (512 * 512) / 4 };
    cp.seg[5]  = { wo_w, WOb,  (512 * 512) / 4 };
    cp.seg[6]  = { ut_w, UTb,  (512 * 512) / 4 };
    cp.seg[7]  = { ug_w, UGb,  (1024 * 512) / 4 };
    cp.seg[8]  = { rq_w, RQb,  (128 * 512) / 4 };
    cp.seg[9]  = { rk_w, RKb,  (128 * 512) / 4 };
    cp.seg[10] = { rv_w, RVb,  (2048 * 512) / 4 };
    cp.seg[11] = { ro_w, ROb,  (512 * 2048) / 4 };
    cast_all<<<dim3(2048, 12), 256, 0, stream>>>(cp);

    // 2) fused stage-1 GEMM: ut | wv(h_s) | rq | wv(mem)   (13 tiles x 128 bm)
    {
        GemmParams g;
        g.seg[0] = { HSb,  UTb, ut_b, UTR, nullptr, 2, 512,  0, 0 };
        g.seg[1] = { HSb,  WVb, wv_b, V1,  nullptr, 6, 512,  0, 4 };
        g.seg[2] = { HSb,  RQb, rq_b, Q2,  nullptr, 0, 128,  0, 8 };
        g.seg[3] = { MEMb, WVb, wv_b, V1,  nullptr, 6, 512,  8, 9 };
        g.nseg = 4; g.tiles_tot = 13;
        gemm_multi<512><<<128 * 13, 256, 0, stream>>>(g);
    }
    // 2b) fused small GEMMs: wk(h_s) | wq(mem) | wk(mem)
    {
        SmallParams sp;
        sp.seg[0] = { HSb,  WKb, wk_b, K1, 5, 0 };
        sp.seg[1] = { MEMb, WQb, wq_b, Q1, 0, 0 };
        sp.seg[2] = { MEMb, WKb, wk_b, K1, 5, 8 };
        gemm_small3<<<768, 256, 0, stream>>>(sp);
    }

    // 3) mean + kk fused
    meankk_kernel<<<Bb, 256, 0, stream>>>(UTR, mem, KKb);

    // 4) attention 1 -> ctx1
    attn1_kernel<<<Bb, 256, 0, stream>>>(Q1, K1, V1, CTX1);

    // 5) fused: wo (tanh -> TMW) | ug (sigmoid -> GATES)   (12 tiles)
    {
        GemmParams g;
        g.seg[0] = { CTX1, WOb, wo_b, TMW,   nullptr, 4,  512, 0, 0 };
        g.seg[1] = { KKb,  UGb, ug_b, GATES, nullptr, 3, 1024, 0, 4 };
        g.nseg = 2; g.tiles_tot = 12;
        gemm_multi<512><<<128 * 12, 256, 0, stream>>>(g);
    }

    // 6) mem_new (writes d_out second half + bf16 copy), x4 vectorized
    memnew_kernel<<<8192, 256, 0, stream>>>(GATES, TMW, mem, out_m, MNB);

    // 7) fused: rk | rv on mem_new   (17 tiles)
    {
        GemmParams g;
        g.seg[0] = { MNB, RKb, rk_b, K2,  nullptr, 0,  128, 0, 0 };
        g.seg[1] = { MNB, RVb, rv_b, RVO, nullptr, 1, 2048, 0, 1 };
        g.nseg = 2; g.tiles_tot = 17;
        gemm_multi<512><<<128 * 17, 256, 0, stream>>>(g);
    }

    // 8) attention 2 -> ctx2
    attn2_kernel<<<Bb, 256, 0, stream>>>(Q2, K2, RVO, CTX2);

    // 9) ro + residual -> h_out (d_out first half)
    {
        GemmParams g;
        g.seg[0] = { CTX2, ROb, ro_b, out, h_s, 7, 512, 0, 0 };
        g.nseg = 1; g.tiles_tot = 4;
        gemm_multi<2048><<<128 * 4, 256, 0, stream>>>(g);
    }

    (void)in_sizes; (void)n_in; (void)out_size; (void)ws_size;
}

// Round 9
// 498.677 us; speedup vs baseline: 1.4568x; 1.4568x over previous
//
#include <hip/hip_runtime.h>

// ---------------------------------------------------------------------------
// Problem constants: B=2048, NS=8, S=8, H=512, WH=1, WK=32, RH=4, RK=32, T=16.
// ---------------------------------------------------------------------------
#define Bb   2048
#define Mrows 16384   // B*8
#define Hd   512

typedef float  f32x4  __attribute__((ext_vector_type(4)));
typedef __bf16 bf16x8 __attribute__((ext_vector_type(8)));
typedef unsigned short us8 __attribute__((ext_vector_type(8)));

__device__ __forceinline__ unsigned short f2bf(float f) {
    unsigned int u = __builtin_bit_cast(unsigned int, f);
    u = u + 0x7FFFu + ((u >> 16) & 1u);   // round-to-nearest-even
    return (unsigned short)(u >> 16);
}
__device__ __forceinline__ float bf2f(unsigned short h) {
    unsigned int u = ((unsigned int)h) << 16;
    return __builtin_bit_cast(float, u);
}

// async global->LDS DMA, 16B per lane; lds dest = wave-uniform base + lane*16
__device__ __forceinline__ void gload_lds16(const unsigned short* g, void* lds) {
    __builtin_amdgcn_global_load_lds(
        (const __attribute__((address_space(1))) unsigned int*)g,
        (__attribute__((address_space(3))) unsigned int*)lds,
        16, 0, 0);
}

// ---------------------------------------------------------------------------
// Workspace layout (bytes); aliases verified by lifetime (rounds 1-7 passed).
// ---------------------------------------------------------------------------
#define MB (1024ull*1024ull)
#define OFF_WQ   0ull
#define OFF_WK   32768ull
#define OFF_WV   65536ull
#define OFF_WO   589824ull
#define OFF_UT   1114112ull
#define OFF_UG   1638400ull
#define OFF_RQ   2686976ull
#define OFF_RK   2818048ull
#define OFF_RV   2949120ull
#define OFF_RO   5046272ull
#define OFF_HS    (8*MB)
#define OFF_MEM   (24*MB)
#define OFF_UTR   (40*MB)
#define OFF_Q1    (60*MB)
#define OFF_K1    (62*MB)
#define OFF_V1    (66*MB)
#define OFF_CTX1  (100*MB)
#define OFF_KK    (116*MB)
#define OFF_TMW   (132*MB)
#define OFF_GATES (148*MB)
#define OFF_MNB   (180*MB)
#define OFF_Q2    (196*MB)
#define OFF_K2    (204*MB)
#define OFF_RVO   (40*MB)    // alias: UTR/Q1/K1/V1/CTX1[0:4MB] dead by then
#define OFF_CTX2  (104*MB)   // alias: CTX1[4:]/KK/TMW/GATES[0:20MB] dead by then

// ---------------------------------------------------------------------------
// Cast f32 -> bf16, 12 segments in one kernel
// ---------------------------------------------------------------------------
struct CastSeg { const float* src; unsigned short* dst; int n4; };
struct CastParams { CastSeg seg[12]; };

__global__ __launch_bounds__(256) void cast_all(CastParams p) {
    CastSeg s = p.seg[blockIdx.y];
    int stride = gridDim.x * blockDim.x;
    for (int i = blockIdx.x * blockDim.x + threadIdx.x; i < s.n4; i += stride) {
        float4 v = reinterpret_cast<const float4*>(s.src)[i];
        ushort4 o;
        o.x = f2bf(v.x); o.y = f2bf(v.y); o.z = f2bf(v.z); o.w = f2bf(v.w);
        reinterpret_cast<ushort4*>(s.dst)[i] = o;
    }
}

// ---------------------------------------------------------------------------
// Epilogue.  MODE: 0 f32  1 bf16  2 relu->bf16  3 sigmoid->bf16
// 4 tanh->bf16  5 f32+row-remap  6 bf16+row-remap  7 f32+residual
// ---------------------------------------------------------------------------
template<int MODE>
__device__ __forceinline__ void store_c(void* out, const float* extra, int row,
                                        int col, int ldo, int remap_off, float v) {
    if (MODE == 0) {
        ((float*)out)[(size_t)row * ldo + col] = v;
    } else if (MODE == 1) {
        ((unsigned short*)out)[(size_t)row * ldo + col] = f2bf(v);
    } else if (MODE == 2) {
        ((unsigned short*)out)[(size_t)row * ldo + col] = f2bf(fmaxf(v, 0.f));
    } else if (MODE == 3) {
        ((unsigned short*)out)[(size_t)row * ldo + col] = f2bf(1.f / (1.f + expf(-v)));
    } else if (MODE == 4) {
        ((unsigned short*)out)[(size_t)row * ldo + col] = f2bf(tanhf(v));
    } else if (MODE == 5) {
        int rr = ((row >> 3) << 4) + (row & 7) + remap_off;
        ((float*)out)[(size_t)rr * ldo + col] = v;
    } else if (MODE == 6) {
        int rr = ((row >> 3) << 4) + (row & 7) + remap_off;
        ((unsigned short*)out)[(size_t)rr * ldo + col] = f2bf(v);
    } else if (MODE == 7) {
        ((float*)out)[(size_t)row * ldo + col] = v + extra[(size_t)row * ldo + col];
    }
}

// ---------------------------------------------------------------------------
// Multi-segment GEMM, R3-proven K-loop (measured best: 510 TF on rv class):
//   128x128 block tile, BK=64, 4 waves (2x2), wave tile 64x64.
//   SINGLE LDS buffer (As+Bs = 32 KB); PLAIN __launch_bounds__(256) — R7's
//   (256,5) capped VGPR at 48 < 64-reg accumulator -> scratch spills
//   (WRITE_SIZE 61->75MB, 145 us/dispatch).  R3's register regime: 92 VGPR,
//   ~4 blocks/CU via LDS+VGPR natural limits.
//   K-step: syncthreads (drain DMAs); ds_read+MFMA; syncthreads; stage kt+1.
//   XOR 16B-chunk swizzle on the GLOBAL source address (LDS linear, m173);
//   ds_read slot = kc ^ (row&7) over 8 slots -> verified 0 bank conflicts.
// ---------------------------------------------------------------------------
struct GemmSeg {
    const unsigned short* A;
    const unsigned short* W;
    const float* bias;
    void* out;
    const float* extra;
    int mode, ldo, remap_off, tile0;
};
struct GemmParams { GemmSeg seg[4]; int nseg; int tiles_tot; };

template<int K>
__global__ __launch_bounds__(256) void gemm_multi(GemmParams p)
{
    constexpr int NT = K / 64;
    __shared__ __align__(16) unsigned short As[128 * 64];
    __shared__ __align__(16) unsigned short Bs[128 * 64];

    // bijective XCD-chunk swizzle (grid always a multiple of 8)
    const int nwg = (int)gridDim.x;
    const int swz = ((int)blockIdx.x & 7) * (nwg >> 3) + ((int)blockIdx.x >> 3);
    const int bm = swz / p.tiles_tot;
    const int tl = swz - bm * p.tiles_tot;

    int si = 0;
    #pragma unroll
    for (int i = 1; i < 4; i++)
        if (i < p.nseg && tl >= p.seg[i].tile0) si = i;
    const unsigned short* Aseg = p.seg[si].A;
    const unsigned short* Wseg = p.seg[si].W;
    const int bn = tl - p.seg[si].tile0;

    const int t = threadIdx.x;
    const int wave = t >> 6, lane = t & 63;
    const int wr = (wave >> 1) * 64;
    const int wc = (wave & 1) * 64;
    const int lrow = lane & 15;
    const int lkh  = lane >> 4;            // 0..3 (k-chunk of fragment)

    // staging: chunk c = wave*256 + j*64 + lane; row=c>>3, slot=c&7;
    // LDS linear (chunk c at byte c*16); source k-chunk = slot ^ (row&7)
    const unsigned short* ga[4];
    const unsigned short* gb[4];
    #pragma unroll
    for (int j = 0; j < 4; j++) {
        int c   = wave * 256 + j * 64 + lane;
        int row = c >> 3;
        int kl  = (c & 7) ^ (row & 7);
        ga[j] = Aseg + (size_t)(bm * 128 + row) * K + kl * 8;
        gb[j] = Wseg + (size_t)(bn * 128 + row) * K + kl * 8;
    }

    // fragment ds_read offsets (elements, swizzled)
    int aof[4][2], bof[4][2];
    #pragma unroll
    for (int m = 0; m < 4; m++) {
        int ra = wr + m * 16 + lrow;
        int rb = wc + m * 16 + lrow;
        #pragma unroll
        for (int kk = 0; kk < 2; kk++) {
            int kc = kk * 4 + lkh;
            aof[m][kk] = ra * 64 + ((kc ^ (ra & 7)) << 3);
            bof[m][kk] = rb * 64 + ((kc ^ (rb & 7)) << 3);
        }
    }

    f32x4 acc[4][4] = {};

    // prologue: stage tile 0
    #pragma unroll
    for (int j = 0; j < 4; j++) {
        gload_lds16(ga[j], (char*)As + (wave * 4 + j) * 1024);
        gload_lds16(gb[j], (char*)Bs + (wave * 4 + j) * 1024);
    }

    for (int kt = 0; kt < NT; ++kt) {
        __syncthreads();   // drains vmcnt -> tile kt resident in LDS
        #pragma unroll
        for (int kk = 0; kk < 2; kk++) {
            bf16x8 af[4], bfr[4];
            #pragma unroll
            for (int m = 0; m < 4; m++)
                af[m] = __builtin_bit_cast(bf16x8,
                            *reinterpret_cast<const us8*>(&As[aof[m][kk]]));
            #pragma unroll
            for (int n = 0; n < 4; n++)
                bfr[n] = __builtin_bit_cast(bf16x8,
                            *reinterpret_cast<const us8*>(&Bs[bof[n][kk]]));
            #pragma unroll
            for (int m = 0; m < 4; m++)
                #pragma unroll
                for (int n = 0; n < 4; n++)
                    acc[m][n] = __builtin_amdgcn_mfma_f32_16x16x32_bf16(
                                    af[m], bfr[n], acc[m][n], 0, 0, 0);
        }
        __syncthreads();   // all waves done reading tile kt
        if (kt + 1 < NT) {
            #pragma unroll
            for (int j = 0; j < 4; j++) {
                gload_lds16(ga[j] + (kt + 1) * 64, (char*)As + (wave * 4 + j) * 1024);
                gload_lds16(gb[j] + (kt + 1) * 64, (char*)Bs + (wave * 4 + j) * 1024);
            }
        }
    }

    // epilogue (uniform branch on segment mode)
    void* outp = p.seg[si].out;
    const float* bias = p.seg[si].bias;
    const float* extra = p.seg[si].extra;
    const int ldo = p.seg[si].ldo, rmo = p.seg[si].remap_off, mode = p.seg[si].mode;

    #define EPI(MODE_)                                                          \
        _Pragma("unroll")                                                       \
        for (int n = 0; n < 4; n++) {                                           \
            int col = bn * 128 + wc + n * 16 + lrow;                            \
            float bv = bias[col];                                               \
            _Pragma("unroll")                                                   \
            for (int m = 0; m < 4; m++) {                                       \
                _Pragma("unroll")                                               \
                for (int r = 0; r < 4; r++) {                                   \
                    int row = bm * 128 + wr + m * 16 + lkh * 4 + r;             \
                    store_c<MODE_>(outp, extra, row, col, ldo, rmo,             \
                                   acc[m][n][r] + bv);                          \
                }                                                               \
            }                                                                   \
        }
    switch (mode) {
        case 0: EPI(0) break;
        case 1: EPI(1) break;
        case 2: EPI(2) break;
        case 3: EPI(3) break;
        case 4: EPI(4) break;
        case 5: EPI(5) break;
        case 6: EPI(6) break;
        default: EPI(7) break;
    }
    #undef EPI
}

// ---------------------------------------------------------------------------
// Fused small GEMMs (N=32, K=512): 3 segments in one dispatch, 256 blocks
// each (bm over M/64).  Direct-global fragments.  Modes: 0 (f32) / 5 (remap).
// ---------------------------------------------------------------------------
struct SmallSeg {
    const unsigned short* A;
    const unsigned short* W;
    const float* bias;
    float* out;
    int mode, remap_off;
};
struct SmallParams { SmallSeg seg[3]; };

__global__ __launch_bounds__(256) void gemm_small3(SmallParams p)
{
    constexpr int K = 512;
    const int si = blockIdx.x >> 8;
    const int bm = blockIdx.x & 255;
    const SmallSeg s = p.seg[si];

    const int wave = threadIdx.x >> 6;
    const int lane = threadIdx.x & 63;
    const int row0 = bm * 64 + wave * 16;
    const int lrow = lane & 15;
    const int lk   = (lane >> 4) << 3;

    f32x4 acc[2] = {};
    const unsigned short* ap  = s.A + (size_t)(row0 + lrow) * K + lk;
    const unsigned short* wp0 = s.W + (size_t)lrow * K + lk;

    #pragma unroll 4
    for (int ks = 0; ks < K; ks += 32) {
        bf16x8 af = __builtin_bit_cast(bf16x8,
                        *reinterpret_cast<const us8*>(ap + ks));
        #pragma unroll
        for (int tt = 0; tt < 2; tt++) {
            bf16x8 bfm = __builtin_bit_cast(bf16x8,
                        *reinterpret_cast<const us8*>(wp0 + (size_t)tt * 16 * K + ks));
            acc[tt] = __builtin_amdgcn_mfma_f32_16x16x32_bf16(af, bfm, acc[tt], 0, 0, 0);
        }
    }

    #pragma unroll
    for (int tt = 0; tt < 2; tt++) {
        int col = tt * 16 + lrow;
        float bv = s.bias[col];
        #pragma unroll
        for (int r = 0; r < 4; r++) {
            int row = row0 + (lane >> 4) * 4 + r;
            float v = acc[tt][r] + bv;
            if (s.mode == 0) {
                s.out[(size_t)row * 32 + col] = v;
            } else {
                int rr = ((row >> 3) << 4) + (row & 7) + s.remap_off;
                s.out[(size_t)rr * 32 + col] = v;
            }
        }
    }
}

// ---------------------------------------------------------------------------
// fused: mean over NS=8 relu rows, then kk = mean + tanh(mem) -> bf16
// block = one batch; thread covers cols {tid, tid+256} for all 8 rows
// ---------------------------------------------------------------------------
__global__ __launch_bounds__(256) void meankk_kernel(
    const unsigned short* __restrict__ UTR, const float* __restrict__ mem,
    unsigned short* __restrict__ KK)
{
    int b = blockIdx.x;
    #pragma unroll
    for (int half = 0; half < 2; half++) {
        int j = threadIdx.x + half * 256;
        float sum = 0.f;
        #pragma unroll
        for (int r = 0; r < 8; r++)
            sum += bf2f(UTR[((size_t)(b * 8 + r) << 9) + j]);
        float mn = sum * 0.125f;
        #pragma unroll
        for (int r = 0; r < 8; r++) {
            size_t idx = ((size_t)(b * 8 + r) << 9) + j;
            KK[idx] = f2bf(mn + tanhf(mem[idx]));
        }
    }
}

// mem_new = sig(ig)*tanh(mem_write) + sig(fg)*mem, x4 vectorized
__global__ __launch_bounds__(256) void memnew_kernel(
    const unsigned short* __restrict__ GATES, const unsigned short* __restrict__ TMW,
    const float* __restrict__ mem, float* __restrict__ out_mem,
    unsigned short* __restrict__ MNB)
{
    int idx = blockIdx.x * 256 + threadIdx.x;   // float4 units: 16384*128
    int m = idx >> 7, j4 = idx & 127;
    ushort4 ig4 = reinterpret_cast<const ushort4*>(GATES + (size_t)m * 1024)[j4];
    ushort4 fg4 = reinterpret_cast<const ushort4*>(GATES + (size_t)m * 1024 + 512)[j4];
    ushort4 tm4 = reinterpret_cast<const ushort4*>(TMW + (size_t)m * 512)[j4];
    float4  mm  = reinterpret_cast<const float4*>(mem + (size_t)m * 512)[j4];
    float4 v;
    v.x = bf2f(ig4.x) * bf2f(tm4.x) + bf2f(fg4.x) * mm.x;
    v.y = bf2f(ig4.y) * bf2f(tm4.y) + bf2f(fg4.y) * mm.y;
    v.z = bf2f(ig4.z) * bf2f(tm4.z) + bf2f(fg4.z) * mm.z;
    v.w = bf2f(ig4.w) * bf2f(tm4.w) + bf2f(fg4.w) * mm.w;
    reinterpret_cast<float4*>(out_mem + (size_t)m * 512)[j4] = v;
    ushort4 o; o.x = f2bf(v.x); o.y = f2bf(v.y); o.z = f2bf(v.z); o.w = f2bf(v.w);
    reinterpret_cast<ushort4*>(MNB + (size_t)m * 512)[j4] = o;
}

// ---------------------------------------------------------------------------
// Attention 1: per batch, q(8,32) k(16,32) v(16,512) -> ctx(8,512) bf16
// ---------------------------------------------------------------------------
__global__ __launch_bounds__(256) void attn1_kernel(
    const float* __restrict__ Q1, const float* __restrict__ K1,
    const unsigned short* __restrict__ V1, unsigned short* __restrict__ CTX1)
{
    int b = blockIdx.x, t = threadIdx.x;
    __shared__ float q[8][32], k[16][32], pr[8][16];
    q[t >> 5][t & 31] = Q1[(size_t)b * 256 + t];
    k[t >> 5][t & 31]       = K1[(size_t)b * 512 + t];
    k[8 + (t >> 5)][t & 31] = K1[(size_t)b * 512 + 256 + t];
    __syncthreads();
    if (t < 128) {
        int s = t >> 4, tt = t & 15;
        float acc = 0.f;
        #pragma unroll
        for (int i = 0; i < 32; i++) acc += q[s][i] * k[tt][i];
        pr[s][tt] = acc * 0.17677669529663687f;   // 1/sqrt(32)
    }
    __syncthreads();
    if (t < 8) {
        float m = -1e30f;
        for (int i = 0; i < 16; i++) m = fmaxf(m, pr[t][i]);
        float e[16], sum = 0.f;
        for (int i = 0; i < 16; i++) { e[i] = expf(pr[t][i] - m); sum += e[i]; }
        float inv = 1.f / sum;
        for (int i = 0; i < 16; i++) pr[t][i] = e[i] * inv;
    }
    __syncthreads();
    int s = t >> 5, d0 = (t & 31) * 16;
    float a[16];
    #pragma unroll
    for (int i = 0; i < 16; i++) a[i] = 0.f;
    for (int tt = 0; tt < 16; tt++) {
        float p = pr[s][tt];
        const unsigned short* vp = V1 + ((size_t)(b * 16 + tt)) * 512 + d0;
        us8 v0 = *reinterpret_cast<const us8*>(vp);
        us8 v1 = *reinterpret_cast<const us8*>(vp + 8);
        #pragma unroll
        for (int i = 0; i < 8; i++) a[i]     += p * bf2f(v0[i]);
        #pragma unroll
        for (int i = 0; i < 8; i++) a[8 + i] += p * bf2f(v1[i]);
    }
    us8 o0, o1;
    #pragma unroll
    for (int i = 0; i < 8; i++) { o0[i] = f2bf(a[i]); o1[i] = f2bf(a[8 + i]); }
    unsigned short* cp = CTX1 + ((size_t)(b * 8 + s)) * 512 + d0;
    *reinterpret_cast<us8*>(cp) = o0;
    *reinterpret_cast<us8*>(cp + 8) = o1;
}

// ---------------------------------------------------------------------------
// Attention 2: per batch, 4 heads: q(8,32) k(8,32) v(8,512) -> ctx(8,2048)
// ---------------------------------------------------------------------------
__global__ __launch_bounds__(256) void attn2_kernel(
    const float* __restrict__ Q2, const float* __restrict__ K2,
    const unsigned short* __restrict__ V2, unsigned short* __restrict__ CTX2)
{
    int b = blockIdx.x, t = threadIdx.x;
    __shared__ float q[8][128], k[8][128], pr[4][8][8];
    for (int i = t; i < 1024; i += 256) {
        q[i >> 7][i & 127] = Q2[(size_t)b * 1024 + i];
        k[i >> 7][i & 127] = K2[(size_t)b * 1024 + i];
    }
    __syncthreads();
    {
        int h = t >> 6, n = (t >> 3) & 7, s = t & 7;
        float acc = 0.f;
        #pragma unroll
        for (int i = 0; i < 32; i++) acc += q[n][h * 32 + i] * k[s][h * 32 + i];
        pr[h][n][s] = acc * 0.17677669529663687f;
    }
    __syncthreads();
    if (t < 32) {
        int h = t >> 3, n = t & 7;
        float m = -1e30f;
        for (int i = 0; i < 8; i++) m = fmaxf(m, pr[h][n][i]);
        float e[8], sum = 0.f;
        for (int i = 0; i < 8; i++) { e[i] = expf(pr[h][n][i] - m); sum += e[i]; }
        float inv = 1.f / sum;
        for (int i = 0; i < 8; i++) pr[h][n][i] = e[i] * inv;
    }
    __syncthreads();
    int n = t >> 5, d0 = (t & 31) * 16;
    for (int h = 0; h < 4; h++) {
        float a[16];
        #pragma unroll
        for (int i = 0; i < 16; i++) a[i] = 0.f;
        for (int s = 0; s < 8; s++) {
            float p = pr[h][n][s];
            const unsigned short* vp = V2 + ((size_t)(b * 8 + s)) * 2048 + h * 512 + d0;
            us8 v0 = *reinterpret_cast<const us8*>(vp);
            us8 v1 = *reinterpret_cast<const us8*>(vp + 8);
            #pragma unroll
            for (int i = 0; i < 8; i++) a[i]     += p * bf2f(v0[i]);
            #pragma unroll
            for (int i = 0; i < 8; i++) a[8 + i] += p * bf2f(v1[i]);
        }
        us8 o0, o1;
        #pragma unroll
        for (int i = 0; i < 8; i++) { o0[i] = f2bf(a[i]); o1[i] = f2bf(a[8 + i]); }
        unsigned short* cp = CTX2 + ((size_t)(b * 8 + n)) * 2048 + h * 512 + d0;
        *reinterpret_cast<us8*>(cp) = o0;
        *reinterpret_cast<us8*>(cp + 8) = o1;
    }
}

// ---------------------------------------------------------------------------
extern "C" void kernel_launch(void* const* d_in, const int* in_sizes, int n_in,
                              void* d_out, int out_size, void* d_ws, size_t ws_size,
                              hipStream_t stream)
{
    const float* h_s  = (const float*)d_in[0];
    const float* mem  = (const float*)d_in[1];
    const float* wq_w = (const float*)d_in[2];  const float* wq_b = (const float*)d_in[3];
    const float* wk_w = (const float*)d_in[4];  const float* wk_b = (const float*)d_in[5];
    const float* wv_w = (const float*)d_in[6];  const float* wv_b = (const float*)d_in[7];
    const float* wo_w = (const float*)d_in[8];  const float* wo_b = (const float*)d_in[9];
    const float* ut_w = (const float*)d_in[10]; const float* ut_b = (const float*)d_in[11];
    const float* ug_w = (const float*)d_in[12]; const float* ug_b = (const float*)d_in[13];
    const float* rq_w = (const float*)d_in[14]; const float* rq_b = (const float*)d_in[15];
    const float* rk_w = (const float*)d_in[16]; const float* rk_b = (const float*)d_in[17];
    const float* rv_w = (const float*)d_in[18]; const float* rv_b = (const float*)d_in[19];
    const float* ro_w = (const float*)d_in[20]; const float* ro_b = (const float*)d_in[21];

    char* ws = (char*)d_ws;
    unsigned short* WQb = (unsigned short*)(ws + OFF_WQ);
    unsigned short* WKb = (unsigned short*)(ws + OFF_WK);
    unsigned short* WVb = (unsigned short*)(ws + OFF_WV);
    unsigned short* WOb = (unsigned short*)(ws + OFF_WO);
    unsigned short* UTb = (unsigned short*)(ws + OFF_UT);
    unsigned short* UGb = (unsigned short*)(ws + OFF_UG);
    unsigned short* RQb = (unsigned short*)(ws + OFF_RQ);
    unsigned short* RKb = (unsigned short*)(ws + OFF_RK);
    unsigned short* RVb = (unsigned short*)(ws + OFF_RV);
    unsigned short* ROb = (unsigned short*)(ws + OFF_RO);
    unsigned short* HSb  = (unsigned short*)(ws + OFF_HS);
    unsigned short* MEMb = (unsigned short*)(ws + OFF_MEM);
    unsigned short* UTR  = (unsigned short*)(ws + OFF_UTR);
    float*          Q1   = (float*)(ws + OFF_Q1);
    float*          K1   = (float*)(ws + OFF_K1);
    unsigned short* V1   = (unsigned short*)(ws + OFF_V1);
    unsigned short* CTX1 = (unsigned short*)(ws + OFF_CTX1);
    unsigned short* KKb  = (unsigned short*)(ws + OFF_KK);
    unsigned short* TMW  = (unsigned short*)(ws + OFF_TMW);
    unsigned short* GATES= (unsigned short*)(ws + OFF_GATES);
    unsigned short* MNB  = (unsigned short*)(ws + OFF_MNB);
    float*          Q2   = (float*)(ws + OFF_Q2);
    float*          K2   = (float*)(ws + OFF_K2);
    unsigned short* RVO  = (unsigned short*)(ws + OFF_RVO);
    unsigned short* CTX2 = (unsigned short*)(ws + OFF_CTX2);

    float* out   = (float*)d_out;            // h_out (16384,512)
    float* out_m = out + (size_t)Mrows * Hd; // mem_new (16384,512)

    // 1) cast inputs + weights to bf16
    CastParams cp;
    cp.seg[0]  = { h_s,  HSb,  (Mrows * Hd) / 4 };
    cp.seg[1]  = { mem,  MEMb, (Mrows * Hd) / 4 };
    cp.seg[2]  = { wq_w, WQb,  (32 * 512) / 4 };
    cp.seg[3]  = { wk_w, WKb,  (32 * 512) / 4 };
    cp.seg[4]  = { wv_w, WVb,  (512 * 512) / 4 };
    cp.seg[5]  = { wo_w, WOb,  (512 * 512) / 4 };
    cp.seg[6]  = { ut_w, UTb,  (512 * 512) / 4 };
    cp.seg[7]  = { ug_w, UGb,  (1024 * 512) / 4 };
    cp.seg[8]  = { rq_w, RQb,  (128 * 512) / 4 };
    cp.seg[9]  = { rk_w, RKb,  (128 * 512) / 4 };
    cp.seg[10] = { rv_w, RVb,  (2048 * 512) / 4 };
    cp.seg[11] = { ro_w, ROb,  (512 * 2048) / 4 };
    cast_all<<<dim3(2048, 12), 256, 0, stream>>>(cp);

    // 2) fused stage-1 GEMM: ut | wv(h_s) | rq | wv(mem)   (13 tiles x 128 bm)
    {
        GemmParams g;
        g.seg[0] = { HSb,  UTb, ut_b, UTR, nullptr, 2, 512,  0, 0 };
        g.seg[1] = { HSb,  WVb, wv_b, V1,  nullptr, 6, 512,  0, 4 };
        g.seg[2] = { HSb,  RQb, rq_b, Q2,  nullptr, 0, 128,  0, 8 };
        g.seg[3] = { MEMb, WVb, wv_b, V1,  nullptr, 6, 512,  8, 9 };
        g.nseg = 4; g.tiles_tot = 13;
        gemm_multi<512><<<128 * 13, 256, 0, stream>>>(g);
    }
    // 2b) fused small GEMMs: wk(h_s) | wq(mem) | wk(mem)
    {
        SmallParams sp;
        sp.seg[0] = { HSb,  WKb, wk_b, K1, 5, 0 };
        sp.seg[1] = { MEMb, WQb, wq_b, Q1, 0, 0 };
        sp.seg[2] = { MEMb, WKb, wk_b, K1, 5, 8 };
        gemm_small3<<<768, 256, 0, stream>>>(sp);
    }

    // 3) mean + kk fused
    meankk_kernel<<<Bb, 256, 0, stream>>>(UTR, mem, KKb);

    // 4) attention 1 -> ctx1
    attn1_kernel<<<Bb, 256, 0, stream>>>(Q1, K1, V1, CTX1);

    // 5) fused: wo (tanh -> TMW) | ug (sigmoid -> GATES)   (12 tiles)
    {
        GemmParams g;
        g.seg[0] = { CTX1, WOb, wo_b, TMW,   nullptr, 4,  512, 0, 0 };
        g.seg[1] = { KKb,  UGb, ug_b, GATES, nullptr, 3, 1024, 0, 4 };
        g.nseg = 2; g.tiles_tot = 12;
        gemm_multi<512><<<128 * 12, 256, 0, stream>>>(g);
    }

    // 6) mem_new (writes d_out second half + bf16 copy), x4 vectorized
    memnew_kernel<<<8192, 256, 0, stream>>>(GATES, TMW, mem, out_m, MNB);

    // 7) fused: rk | rv on mem_new   (17 tiles)
    {
        GemmParams g;
        g.seg[0] = { MNB, RKb, rk_b, K2,  nullptr, 0,  128, 0, 0 };
        g.seg[1] = { MNB, RVb, rv_b, RVO, nullptr, 1, 2048, 0, 1 };
        g.nseg = 2; g.tiles_tot = 17;
        gemm_multi<512><<<128 * 17, 256, 0, stream>>>(g);
    }

    // 8) attention 2 -> ctx2
    attn2_kernel<<<Bb, 256, 0, stream>>>(Q2, K2, RVO, CTX2);

    // 9) ro + residual -> h_out (d_out first half)
    {
        GemmParams g;
        g.seg[0] = { CTX2, ROb, ro_b, out, h_s, 7, 512, 0, 0 };
        g.nseg = 1; g.tiles_tot = 4;
        gemm_multi<2048><<<128 * 4, 256, 0, stream>>>(g);
    }

    (void)in_sizes; (void)n_in; (void)out_size; (void)ws_size;
}